// Round 1
// baseline (2176.299 us; speedup 1.0000x reference)
//
#include <hip/hip_runtime.h>

#define T_LEN 4096

typedef float v2f __attribute__((ext_vector_type(2)));

__device__ __forceinline__ float frcp(float x) { return __builtin_amdgcn_rcpf(x); }
__device__ __forceinline__ float fexp2(float x) { return __builtin_amdgcn_exp2f(x); }

__device__ __forceinline__ float rl(float v, int lane) {
  // wave-uniform read of lane's value -> SGPR (usable as scalar VALU operand)
  return __int_as_float(__builtin_amdgcn_readlane(__float_as_int(v), lane));
}
__device__ __forceinline__ float rfl(float v) {
  return __int_as_float(__builtin_amdgcn_readfirstlane(__float_as_int(v)));
}

// packed dual-FMA: acc = w*s + acc (VOP3P, full-rate fp32 pairs).
// s is a wave-uniform SGPR pair (the single allowed scalar operand).
__device__ __forceinline__ void pk_fma_s(v2f& acc, v2f w, v2f s) {
  asm("v_pk_fma_f32 %0, %1, %2, %0" : "+v"(acc) : "v"(w), "s"(s));
}

// quad_perm DPP butterfly adds: xor1 = 0xB1, xor2 = 0x4E
template <int CTRL>
__device__ __forceinline__ float dpp_add(float x) {
  int t = __builtin_amdgcn_mov_dpp(__float_as_int(x), CTRL, 0xF, 0xF, true);
  return x + __int_as_float(t);
}

#define NLN2f (-0.6931471805599453f)

// ---- per-step phase helpers (called once per batch element; all inlined,
// constant indices after unroll -> registers) ----

__device__ __forceinline__ float layer1_silu(float m_t, const v2f* W1y2,
                                             const v2f* yu2) {
  v2f ma; ma.x = m_t;  ma.y = 0.0f;
  v2f mb; mb.x = 0.0f; mb.y = 0.0f;
#pragma unroll
  for (int k = 0; k < 4; ++k) {
    pk_fma_s(ma, W1y2[k],     yu2[k]);
    pk_fma_s(mb, W1y2[4 + k], yu2[4 + k]);
  }
  const v2f ms = ma + mb;
  const float m = ms.x + ms.y;
  // silu: u * sigmoid(u), u = -ln2 * m, exp(-u) = exp2(m)
  const float eM = fexp2(m);
  return (m * NLN2f) * frcp(1.0f + eM);
}

__device__ __forceinline__ void g_dots(float s, const v2f* G0p, const v2f* G1p,
                                       float bg0p, float bg1p,
                                       v2f& gs0, v2f& gs1) {
  v2f su[8];  // s from lanes 16..31 (cvf layer-1 rows)
#pragma unroll
  for (int k = 0; k < 8; ++k) {
    v2f r; r.x = rl(s, 16 + 2 * k); r.y = rl(s, 17 + 2 * k);
    su[k] = r;
  }
  v2f ga; ga.x = bg0p; ga.y = 0.0f;
  v2f gc; gc.x = 0.0f; gc.y = 0.0f;
  v2f gb; gb.x = bg1p; gb.y = 0.0f;
  v2f gd; gd.x = 0.0f; gd.y = 0.0f;
#pragma unroll
  for (int k = 0; k < 4; ++k) {
    pk_fma_s(ga, G0p[k],     su[k]);
    pk_fma_s(gc, G0p[4 + k], su[4 + k]);
    pk_fma_s(gb, G1p[k],     su[k]);
    pk_fma_s(gd, G1p[4 + k], su[4 + k]);
  }
  gs0 = ga + gc;
  gs1 = gb + gd;
}

__device__ __forceinline__ v2f f_dots(float s, const v2f* W2p, float b2p) {
  v2f su[8];  // s from lanes 0..15 (vf layer-1 rows)
#pragma unroll
  for (int k = 0; k < 8; ++k) {
    v2f r; r.x = rl(s, 2 * k); r.y = rl(s, 2 * k + 1);
    su[k] = r;
  }
  v2f fa; fa.x = b2p;  fa.y = 0.0f;
  v2f fb; fb.x = 0.0f; fb.y = 0.0f;
#pragma unroll
  for (int k = 0; k < 4; ++k) {
    pk_fma_s(fa, W2p[k],     su[k]);
    pk_fma_s(fb, W2p[4 + k], su[4 + k]);
  }
  return fa + fb;
}

__device__ __forceinline__ float finish_step(v2f gs0, v2f gs1, v2f fs, v2f dx,
                                             float y_own) {
  // tanh(x) = 1 - 2/(1+exp2(x')) with x' pre-scaled by 2*log2e
  const float g0v = fmaf(-2.0f, frcp(1.0f + fexp2(gs0.x + gs0.y)), 1.0f);
  const float g1v = fmaf(-2.0f, frcp(1.0f + fexp2(gs1.x + gs1.y)), 1.0f);
  const float fv  = fmaf(-2.0f, frcp(1.0f + fexp2(fs.x + fs.y)), 1.0f);
  float pr = fmaf(g0v, dx.x, g1v * dx.y);
  pr = dpp_add<0xB1>(pr);
  pr = dpp_add<0x4E>(pr);
  return y_own + (fv + pr);
}

__device__ __forceinline__ void y_bcast(float yn, v2f* yu2) {
#pragma unroll
  for (int k = 0; k < 8; ++k) {
    v2f r; r.x = rl(yn, 8 * k); r.y = rl(yn, 8 * k + 4);
    yu2[k] = r;
  }
}

__device__ __forceinline__ float readout(const float* __restrict__ rW,
                                         float rb0, const v2f* yu2) {
  float o = rb0;
#pragma unroll
  for (int k = 0; k < 8; ++k) {
    o = fmaf(rW[2 * k],     yu2[k].x, o);
    o = fmaf(rW[2 * k + 1], yu2[k].y, o);
  }
  return o;
}

// One wave (64 lanes) per TWO batch elements; block = 1 wave => no barriers.
// Lane roles per element (identical for both, weights shared in VGPRs):
//   z-dot  : row h16 = l&15 of (p ? cW1 : vW1), p=(l>>4)&1 -> s[l&31]
//   f-dot  : row hf = l>>2 of vW2 (dup x4)
//   g-dots : rows 2l, 2l+1 of cW2 => g[hf][d0], g[hf][d0+1], d0=(2l)&7
//   reduce : quad DPP butterfly; lane keeps y[hf]; y broadcast via readlane.
// The two elements are independent dependency chains interleaved at phase
// granularity -> fills the ~60% VALU stall slots of the single-chain version.
__global__ __launch_bounds__(64, 1) void disc_kernel(
    const float* __restrict__ ts, const float* __restrict__ ys,
    const float* __restrict__ iW1, const float* __restrict__ ib1,
    const float* __restrict__ iW2, const float* __restrict__ ib2,
    const float* __restrict__ vW1, const float* __restrict__ vb1,
    const float* __restrict__ vW2, const float* __restrict__ vb2,
    const float* __restrict__ cW1, const float* __restrict__ cb1,
    const float* __restrict__ cW2, const float* __restrict__ cb2,
    const float* __restrict__ rW, const float* __restrict__ rb,
    float* __restrict__ out)
{
  const int b0  = blockIdx.x * 2;
  const int l   = threadIdx.x;
  const int h16 = l & 15;
  const int p   = (l >> 4) & 1;
  const int hf  = l >> 2;
  const int d0  = (2 * l) & 7;

  __shared__ __align__(16) float sbuf0[16];
  __shared__ __align__(16) float sbuf1[16];
  __shared__ __align__(16) float ybuf0[16];
  __shared__ __align__(16) float ybuf1[16];
  __shared__ __align__(16) float xbuf0[1024];  // elem0: 2 x 64 dx-rows
  __shared__ __align__(16) float xbuf1[1024];  // elem1: 2 x 64 dx-rows

  const float* __restrict__ ysb0 = ys + (size_t)b0 * (T_LEN * 8);
  const float* __restrict__ ysb1 = ysb0 + (size_t)(T_LEN * 8);

  const float NL2E = -1.4426950408889634f;                 // -log2(e)
  const float TSW  = 2.0f * 1.4426950408889634f * 0.909f;  // weight scale (tanh arg)
  const float TSB  = 2.0f * 1.4426950408889634f;           // bias scale (tanh arg)

  // ---- per-lane weights (scaled), shared by both elements ----
  float w1t, b1m;
  v2f W1y2[8];
  {
    const float* W1 = p ? cW1 : vW1;
    const float* bv = p ? cb1 : vb1;
    w1t = NL2E * W1[h16 * 17];
    b1m = NL2E * bv[h16];
#pragma unroll
    for (int k = 0; k < 8; ++k) {
      v2f w; w.x = NL2E * W1[h16 * 17 + 1 + 2 * k];
             w.y = NL2E * W1[h16 * 17 + 2 + 2 * k];
      W1y2[k] = w;
    }
  }
  v2f W2p[8], G0p[8], G1p[8];
#pragma unroll
  for (int k = 0; k < 8; ++k) {
    v2f a; a.x = TSW * vW2[hf * 16 + 2 * k]; a.y = TSW * vW2[hf * 16 + 2 * k + 1];
    W2p[k] = a;
    v2f c0; c0.x = TSW * cW2[(2 * l) * 16 + 2 * k]; c0.y = TSW * cW2[(2 * l) * 16 + 2 * k + 1];
    G0p[k] = c0;
    v2f c1; c1.x = TSW * cW2[(2 * l + 1) * 16 + 2 * k]; c1.y = TSW * cW2[(2 * l + 1) * 16 + 2 * k + 1];
    G1p[k] = c1;
  }
  const float b2p  = TSB * vb2[hf];
  const float bg0p = TSB * cb2[2 * l];
  const float bg1p = TSB * cb2[2 * l + 1];

  const float t0 = ts[0];

  // ---- initial hidden states (cold path, via LDS; same-wave DS is ordered) ----
  float y_own0, y_own1;
  v2f yu20[8], yu21[8];  // wave-uniform y pairs in SGPRs
  {
    float acc = ib1[h16] + iW1[h16 * 9] * t0;
#pragma unroll
    for (int d = 0; d < 8; ++d) acc = fmaf(iW1[h16 * 9 + 1 + d], ysb0[d], acc);
    sbuf0[h16] = fmaxf(acc, 0.0f);
    float accB = ib1[h16] + iW1[h16 * 9] * t0;
#pragma unroll
    for (int d = 0; d < 8; ++d) accB = fmaf(iW1[h16 * 9 + 1 + d], ysb1[d], accB);
    sbuf1[h16] = fmaxf(accB, 0.0f);

    float acc2 = ib2[h16];
    float acc3 = ib2[h16];
#pragma unroll
    for (int k = 0; k < 16; ++k) {
      const float w = iW2[h16 * 16 + k];
      acc2 = fmaf(w, sbuf0[k], acc2);
      acc3 = fmaf(w, sbuf1[k], acc3);
    }
    ybuf0[h16] = acc2;
    ybuf1[h16] = acc3;
    y_own0 = ybuf0[hf];
    y_own1 = ybuf1[hf];
#pragma unroll
    for (int k = 0; k < 8; ++k) {
      v2f r0; r0.x = rfl(ybuf0[2 * k]); r0.y = rfl(ybuf0[2 * k + 1]);
      yu20[k] = r0;
      v2f r1; r1.x = rfl(ybuf1[2 * k]); r1.y = rfl(ybuf1[2 * k + 1]);
      yu21[k] = r1;
    }
  }

  // ---- readout at t0 (o is wave-uniform; lane 0 stores both) ----
  {
    const float rb0 = rb[0];
    const float o0 = readout(rW, rb0, yu20);
    const float o1 = readout(rW, rb0, yu21);
    if (l == 0) {
      out[2 * b0]     = o0;
      out[2 * b0 + 2] = o1;
    }
  }

  // ---- dx staging: 64-row chunks, double-buffered, prefetch next chunk ----
  const int CLAMP = T_LEN * 8 - 4;
  float4 A0, B0, C0, D0, A1, B1, C1, D1;
  {
    const int f0 = l * 8;
    A0 = *(const float4*)(ysb0 + min(f0,      CLAMP));
    B0 = *(const float4*)(ysb0 + min(f0 + 4,  CLAMP));
    C0 = *(const float4*)(ysb0 + min(f0 + 8,  CLAMP));
    D0 = *(const float4*)(ysb0 + min(f0 + 12, CLAMP));
    A1 = *(const float4*)(ysb1 + min(f0,      CLAMP));
    B1 = *(const float4*)(ysb1 + min(f0 + 4,  CLAMP));
    C1 = *(const float4*)(ysb1 + min(f0 + 8,  CLAMP));
    D1 = *(const float4*)(ysb1 + min(f0 + 12, CLAMP));
    float4 e0, e1;
    e0.x = C0.x - A0.x; e0.y = C0.y - A0.y; e0.z = C0.z - A0.z; e0.w = C0.w - A0.w;
    e1.x = D0.x - B0.x; e1.y = D0.y - B0.y; e1.z = D0.z - B0.z; e1.w = D0.w - B0.w;
    *(float4*)(xbuf0 + l * 8)     = e0;
    *(float4*)(xbuf0 + l * 8 + 4) = e1;
    e0.x = C1.x - A1.x; e0.y = C1.y - A1.y; e0.z = C1.z - A1.z; e0.w = C1.w - A1.w;
    e1.x = D1.x - B1.x; e1.y = D1.y - B1.y; e1.z = D1.z - B1.z; e1.w = D1.w - B1.w;
    *(float4*)(xbuf1 + l * 8)     = e0;
    *(float4*)(xbuf1 + l * 8 + 4) = e1;
  }

  float t = t0;
  for (int c = 0; c < 64; ++c) {
    // prefetch chunk c+1 for both elements (clamped; last chunk re-reads itself)
    {
      const int cn = min(c + 1, 63);
      const int f0 = cn * 512 + l * 8;
      A0 = *(const float4*)(ysb0 + min(f0,      CLAMP));
      B0 = *(const float4*)(ysb0 + min(f0 + 4,  CLAMP));
      C0 = *(const float4*)(ysb0 + min(f0 + 8,  CLAMP));
      D0 = *(const float4*)(ysb0 + min(f0 + 12, CLAMP));
      A1 = *(const float4*)(ysb1 + min(f0,      CLAMP));
      B1 = *(const float4*)(ysb1 + min(f0 + 4,  CLAMP));
      C1 = *(const float4*)(ysb1 + min(f0 + 8,  CLAMP));
      D1 = *(const float4*)(ysb1 + min(f0 + 12, CLAMP));
    }
    const float* __restrict__ xb0 = xbuf0 + (c & 1) * 512;
    const float* __restrict__ xb1 = xbuf1 + (c & 1) * 512;
    const int base = c * 64;
    const int nsteps = min(64, (T_LEN - 1) - base);
    for (int j = 0; j < nsteps; ++j) {
      // dx reads first: ds_read latency hides under the layer-1 chains
      const v2f dx0 = *(const v2f*)(xb0 + j * 8 + d0);
      const v2f dx1 = *(const v2f*)(xb1 + j * 8 + d0);

      // m_t is role-dependent but element-independent: compute once
      const float m_t = fmaf(w1t, t, b1m);

      // two independent chains, phase-interleaved
      const float s0 = layer1_silu(m_t, W1y2, yu20);
      const float s1 = layer1_silu(m_t, W1y2, yu21);

      v2f gs00, gs01; g_dots(s0, G0p, G1p, bg0p, bg1p, gs00, gs01);
      v2f gs10, gs11; g_dots(s1, G0p, G1p, bg0p, bg1p, gs10, gs11);

      const v2f fs0 = f_dots(s0, W2p, b2p);
      const v2f fs1 = f_dots(s1, W2p, b2p);

      y_own0 = finish_step(gs00, gs01, fs0, dx0, y_own0);
      y_own1 = finish_step(gs10, gs11, fs1, dx1, y_own1);

      y_bcast(y_own0, yu20);
      y_bcast(y_own1, yu21);

      t += 1.0f;
    }
    // write prefetched chunk into the other buffers (vmcnt drain is off the
    // step critical path: 64 steps of compute covered the load latency)
    float* xbn0 = xbuf0 + ((c + 1) & 1) * 512;
    float* xbn1 = xbuf1 + ((c + 1) & 1) * 512;
    float4 e0, e1;
    e0.x = C0.x - A0.x; e0.y = C0.y - A0.y; e0.z = C0.z - A0.z; e0.w = C0.w - A0.w;
    e1.x = D0.x - B0.x; e1.y = D0.y - B0.y; e1.z = D0.z - B0.z; e1.w = D0.w - B0.w;
    *(float4*)(xbn0 + l * 8)     = e0;
    *(float4*)(xbn0 + l * 8 + 4) = e1;
    e0.x = C1.x - A1.x; e0.y = C1.y - A1.y; e0.z = C1.z - A1.z; e0.w = C1.w - A1.w;
    e1.x = D1.x - B1.x; e1.y = D1.y - B1.y; e1.z = D1.z - B1.z; e1.w = D1.w - B1.w;
    *(float4*)(xbn1 + l * 8)     = e0;
    *(float4*)(xbn1 + l * 8 + 4) = e1;
  }

  // ---- readout at t1 ----
  {
    const float rb0 = rb[0];
    const float o0 = readout(rW, rb0, yu20);
    const float o1 = readout(rW, rb0, yu21);
    if (l == 0) {
      out[2 * b0 + 1] = o0;
      out[2 * b0 + 3] = o1;
    }
  }
}

extern "C" void kernel_launch(void* const* d_in, const int* in_sizes, int n_in,
                              void* d_out, int out_size, void* d_ws, size_t ws_size,
                              hipStream_t stream) {
  (void)in_sizes; (void)n_in; (void)out_size; (void)d_ws; (void)ws_size;
  const float* ts  = (const float*)d_in[0];
  const float* ys  = (const float*)d_in[1];
  const float* iW1 = (const float*)d_in[2];
  const float* ib1 = (const float*)d_in[3];
  const float* iW2 = (const float*)d_in[4];
  const float* ib2 = (const float*)d_in[5];
  const float* vW1 = (const float*)d_in[6];
  const float* vb1 = (const float*)d_in[7];
  const float* vW2 = (const float*)d_in[8];
  const float* vb2 = (const float*)d_in[9];
  const float* cW1 = (const float*)d_in[10];
  const float* cb1 = (const float*)d_in[11];
  const float* cW2 = (const float*)d_in[12];
  const float* cb2 = (const float*)d_in[13];
  const float* rW  = (const float*)d_in[14];
  const float* rb  = (const float*)d_in[15];
  float* out = (float*)d_out;
  hipLaunchKernelGGL(disc_kernel, dim3(256), dim3(64), 0, stream,
                     ts, ys, iW1, ib1, iW2, ib2, vW1, vb1, vW2, vb2,
                     cW1, cb1, cW2, cb2, rW, rb, out);
}

// Round 3
// 1195.276 us; speedup vs baseline: 1.8207x; 1.8207x over previous
//
#include <hip/hip_runtime.h>

#define T_LEN 4096

typedef float v2f __attribute__((ext_vector_type(2)));
typedef float v4f __attribute__((ext_vector_type(4)));

__device__ __forceinline__ float frcp(float x) { return __builtin_amdgcn_rcpf(x); }
__device__ __forceinline__ float fexp2(float x) { return __builtin_amdgcn_exp2f(x); }

// packed dual-FMA: acc = w*s + acc (VOP3P, full-rate fp32 pairs, all-VGPR).
__device__ __forceinline__ void pk_fma_v(v2f& acc, v2f w, v2f s) {
  asm("v_pk_fma_f32 %0, %1, %2, %0" : "+v"(acc) : "v"(w), "v"(s));
}

// quad_perm DPP butterfly adds: xor1 = 0xB1, xor2 = 0x4E
template <int CTRL>
__device__ __forceinline__ float dpp_add(float x) {
  int t = __builtin_amdgcn_mov_dpp(__float_as_int(x), CTRL, 0xF, 0xF, true);
  return x + __int_as_float(t);
}

// compile-time fence: forbids reordering LDS publish vs dependent broadcast
// reads (float stores vs v4f reinterpret loads could be TBAA-noalias).
__device__ __forceinline__ void cfence() { asm volatile("" ::: "memory"); }

#define NLN2f (-0.6931471805599453f)

// readout: y[0..15] lives in cbuf[64..79]; all lanes compute (uniform), lane 0 stores.
__device__ __forceinline__ float readout_lds(const float* cb,
                                             const float* __restrict__ rW,
                                             float rb0) {
  v4f a = *(const v4f*)(cb + 64);
  v4f b = *(const v4f*)(cb + 68);
  v4f c = *(const v4f*)(cb + 72);
  v4f d = *(const v4f*)(cb + 76);
  float o = rb0;
  o = fmaf(rW[0],  a.x, o); o = fmaf(rW[1],  a.y, o);
  o = fmaf(rW[2],  a.z, o); o = fmaf(rW[3],  a.w, o);
  o = fmaf(rW[4],  b.x, o); o = fmaf(rW[5],  b.y, o);
  o = fmaf(rW[6],  b.z, o); o = fmaf(rW[7],  b.w, o);
  o = fmaf(rW[8],  c.x, o); o = fmaf(rW[9],  c.y, o);
  o = fmaf(rW[10], c.z, o); o = fmaf(rW[11], c.w, o);
  o = fmaf(rW[12], d.x, o); o = fmaf(rW[13], d.y, o);
  o = fmaf(rW[14], d.z, o); o = fmaf(rW[15], d.w, o);
  return o;
}

// One wave (64 lanes) per batch element; block = 1 wave => no barriers.
// Broadcasts go through LDS (same-wave DS ops execute in order) instead of
// v_readlane:
//   layer-1: every lane does the full 16-wide y-dot; y[0..15] read as 4x b128
//            uniform-address broadcasts from cbuf[64..79].
//   s:       every lane ds_writes s to slot l; g-side reads slots 16..31 as
//            4 uniform b128 broadcasts; f-side reads its quartet (1x b128,
//            4 distinct addrs x 16-lane broadcast), quarter-dot + quad DPP
//            butterfly before tanh.
// exp2 folding as before: W1 scaled by -log2e, W2/G by 2*log2e*0.909,
// biases by the matching factor.
__global__ __launch_bounds__(64) void disc_kernel(
    const float* __restrict__ ts, const float* __restrict__ ys,
    const float* __restrict__ iW1, const float* __restrict__ ib1,
    const float* __restrict__ iW2, const float* __restrict__ ib2,
    const float* __restrict__ vW1, const float* __restrict__ vb1,
    const float* __restrict__ vW2, const float* __restrict__ vb2,
    const float* __restrict__ cW1, const float* __restrict__ cb1,
    const float* __restrict__ cW2, const float* __restrict__ cb2,
    const float* __restrict__ rW, const float* __restrict__ rb,
    float* __restrict__ out)
{
  const int b   = blockIdx.x;
  const int l   = threadIdx.x;
  const int h16 = l & 15;
  const int p   = (l >> 4) & 1;
  const int hf  = l >> 2;
  const int d0  = (2 * l) & 7;
  const int q4  = 4 * (l & 3);        // f-quartet base (s_f columns)
  const int ywslot = ((l & 3) == 0) ? (64 + hf) : (80 + l);  // y write / dump

  __shared__ __align__(16) float sbuf[16];    // init relu staging
  __shared__ __align__(16) float cbuf[160];   // [0..63] s, [64..79] y, [80..143] dump
  __shared__ __align__(16) float xbuf[1024];  // 2 x 64 dx-rows (8 floats each)

  const float* __restrict__ ysb = ys + (size_t)b * (T_LEN * 8);

  const float NL2E = -1.4426950408889634f;                 // -log2(e)
  const float TSW  = 2.0f * 1.4426950408889634f * 0.909f;  // weight scale (tanh arg)
  const float TSB  = 2.0f * 1.4426950408889634f;           // bias scale (tanh arg)

  // ---- per-lane weights (scaled) ----
  float w1t, b1m;
  v2f W1y2[8];
  {
    const float* W1 = p ? cW1 : vW1;
    const float* bv = p ? cb1 : vb1;
    w1t = NL2E * W1[h16 * 17];
    b1m = NL2E * bv[h16];
#pragma unroll
    for (int k = 0; k < 8; ++k) {
      v2f w; w.x = NL2E * W1[h16 * 17 + 1 + 2 * k];
             w.y = NL2E * W1[h16 * 17 + 2 + 2 * k];
      W1y2[k] = w;
    }
  }
  v2f W2q[2];
#pragma unroll
  for (int j = 0; j < 2; ++j) {
    v2f w; w.x = TSW * vW2[hf * 16 + q4 + 2 * j];
           w.y = TSW * vW2[hf * 16 + q4 + 2 * j + 1];
    W2q[j] = w;
  }
  v2f G0p[8], G1p[8];
#pragma unroll
  for (int k = 0; k < 8; ++k) {
    v2f c0; c0.x = TSW * cW2[(2 * l) * 16 + 2 * k]; c0.y = TSW * cW2[(2 * l) * 16 + 2 * k + 1];
    G0p[k] = c0;
    v2f c1; c1.x = TSW * cW2[(2 * l + 1) * 16 + 2 * k]; c1.y = TSW * cW2[(2 * l + 1) * 16 + 2 * k + 1];
    G1p[k] = c1;
  }
  const float b2p  = TSB * vb2[hf];
  const float bg0p = TSB * cb2[2 * l];
  const float bg1p = TSB * cb2[2 * l + 1];

  const float t0 = ts[0];

  // ---- initial hidden state (cold path, via LDS; same-wave DS is ordered) ----
  float y_own;
  {
    float acc = ib1[h16] + iW1[h16 * 9] * t0;
#pragma unroll
    for (int d = 0; d < 8; ++d) acc = fmaf(iW1[h16 * 9 + 1 + d], ysb[d], acc);
    sbuf[h16] = fmaxf(acc, 0.0f);
    cfence();
    float acc2 = ib2[h16];
#pragma unroll
    for (int k = 0; k < 16; ++k) acc2 = fmaf(iW2[h16 * 16 + k], sbuf[k], acc2);
    cbuf[64 + h16] = acc2;     // duplicate same-addr same-value writes (init only)
    cfence();
    y_own = cbuf[64 + hf];
  }

  // ---- readout at t0 ----
  {
    const float o = readout_lds(cbuf, rW, rb[0]);
    if (l == 0) out[2 * b] = o;
  }

  // ---- dx staging: 64-row chunks, double-buffered, prefetch next chunk ----
  const int CLAMP = T_LEN * 8 - 4;
  float4 A, Bq, Cq, Dq;
  {
    const int f0 = l * 8;
    A  = *(const float4*)(ysb + min(f0,      CLAMP));
    Bq = *(const float4*)(ysb + min(f0 + 4,  CLAMP));
    Cq = *(const float4*)(ysb + min(f0 + 8,  CLAMP));
    Dq = *(const float4*)(ysb + min(f0 + 12, CLAMP));
    float4 e0, e1;
    e0.x = Cq.x - A.x;  e0.y = Cq.y - A.y;  e0.z = Cq.z - A.z;  e0.w = Cq.w - A.w;
    e1.x = Dq.x - Bq.x; e1.y = Dq.y - Bq.y; e1.z = Dq.z - Bq.z; e1.w = Dq.w - Bq.w;
    *(float4*)(xbuf + l * 8)     = e0;
    *(float4*)(xbuf + l * 8 + 4) = e1;
    cfence();
  }

  float t = t0;
  for (int c = 0; c < 64; ++c) {
    // prefetch chunk c+1 (clamped; last chunk re-reads itself, harmless)
    {
      const int cn = min(c + 1, 63);
      const int f0 = cn * 512 + l * 8;
      A  = *(const float4*)(ysb + min(f0,      CLAMP));
      Bq = *(const float4*)(ysb + min(f0 + 4,  CLAMP));
      Cq = *(const float4*)(ysb + min(f0 + 8,  CLAMP));
      Dq = *(const float4*)(ysb + min(f0 + 12, CLAMP));
    }
    const float* __restrict__ xb = xbuf + (c & 1) * 512;
    const int base = c * 64;
    const int nsteps = min(64, (T_LEN - 1) - base);
    for (int j = 0; j < nsteps; ++j) {
      // y broadcasts (prev step's ds_write; same-wave ordered, fenced)
      const v4f ya = *(const v4f*)(cbuf + 64);
      const v4f yb = *(const v4f*)(cbuf + 68);
      const v4f yc = *(const v4f*)(cbuf + 72);
      const v4f yd = *(const v4f*)(cbuf + 76);
      // dx read early: ds_read latency hides under layer-1
      const v2f dx = *(const v2f*)(xb + j * 8 + d0);

      // layer-1 full 16-wide dot (8 pk, two chains)
      const float m_t = fmaf(w1t, t, b1m);
      v2f ma; ma.x = m_t;  ma.y = 0.0f;
      v2f mb; mb.x = 0.0f; mb.y = 0.0f;
      pk_fma_v(ma, W1y2[0], ya.xy);
      pk_fma_v(ma, W1y2[1], ya.zw);
      pk_fma_v(ma, W1y2[2], yb.xy);
      pk_fma_v(ma, W1y2[3], yb.zw);
      pk_fma_v(mb, W1y2[4], yc.xy);
      pk_fma_v(mb, W1y2[5], yc.zw);
      pk_fma_v(mb, W1y2[6], yd.xy);
      pk_fma_v(mb, W1y2[7], yd.zw);
      const v2f ms = ma + mb;
      const float m = ms.x + ms.y;

      // silu: u * sigmoid(u), u = -ln2 * m, exp(-u) = exp2(m)
      const float eM = fexp2(m);
      const float s  = (m * NLN2f) * frcp(1.0f + eM);

      // publish s; fenced so broadcast reads can't be hoisted above the write
      cbuf[l] = s;
      cfence();
      const v4f g0 = *(const v4f*)(cbuf + 16);   // s_g[0..3]   (uniform bcast)
      const v4f g1 = *(const v4f*)(cbuf + 20);   // s_g[4..7]
      const v4f g2 = *(const v4f*)(cbuf + 24);   // s_g[8..11]
      const v4f g3 = *(const v4f*)(cbuf + 28);   // s_g[12..15]
      const v4f sf = *(const v4f*)(cbuf + q4);   // s_f quartet (4-addr bcast)

      // g-dots: 2 rows x 16, two chains each (all-VGPR pk)
      v2f ga; ga.x = bg0p; ga.y = 0.0f;
      v2f gc; gc.x = 0.0f; gc.y = 0.0f;
      v2f gb; gb.x = bg1p; gb.y = 0.0f;
      v2f gd; gd.x = 0.0f; gd.y = 0.0f;
      pk_fma_v(ga, G0p[0], g0.xy); pk_fma_v(ga, G0p[1], g0.zw);
      pk_fma_v(ga, G0p[2], g1.xy); pk_fma_v(ga, G0p[3], g1.zw);
      pk_fma_v(gc, G0p[4], g2.xy); pk_fma_v(gc, G0p[5], g2.zw);
      pk_fma_v(gc, G0p[6], g3.xy); pk_fma_v(gc, G0p[7], g3.zw);
      pk_fma_v(gb, G1p[0], g0.xy); pk_fma_v(gb, G1p[1], g0.zw);
      pk_fma_v(gb, G1p[2], g1.xy); pk_fma_v(gb, G1p[3], g1.zw);
      pk_fma_v(gd, G1p[4], g2.xy); pk_fma_v(gd, G1p[5], g2.zw);
      pk_fma_v(gd, G1p[6], g3.xy); pk_fma_v(gd, G1p[7], g3.zw);

      // f quarter-dot + quad butterfly BEFORE tanh (bias once, post-reduce)
      v2f fa; fa.x = 0.0f; fa.y = 0.0f;
      pk_fma_v(fa, W2q[0], sf.xy);
      pk_fma_v(fa, W2q[1], sf.zw);
      float fp = fa.x + fa.y;
      fp = dpp_add<0xB1>(fp);
      fp = dpp_add<0x4E>(fp);
      const float farg = fp + b2p;

      // tanh(x) = 1 - 2/(1+exp2(x')) with x' pre-scaled by 2*log2e
      const v2f gs0 = ga + gc;
      const v2f gs1 = gb + gd;
      const float g0v = fmaf(-2.0f, frcp(1.0f + fexp2(gs0.x + gs0.y)), 1.0f);
      const float g1v = fmaf(-2.0f, frcp(1.0f + fexp2(gs1.x + gs1.y)), 1.0f);
      const float fv  = fmaf(-2.0f, frcp(1.0f + fexp2(farg)), 1.0f);

      // einsum partial + quad butterfly reduce over d
      float pr = fmaf(g0v, dx.x, g1v * dx.y);
      pr = dpp_add<0xB1>(pr);
      pr = dpp_add<0x4E>(pr);

      y_own = y_own + (fv + pr);
      cbuf[ywslot] = y_own;   // publish y for next step (dump lanes -> 80+l)
      cfence();
      t += 1.0f;
    }
    // write prefetched chunk into the other buffer (vmcnt drain is off the
    // step critical path: 64 steps of compute covered the load latency)
    float* xbn = xbuf + ((c + 1) & 1) * 512;
    float4 e0, e1;
    e0.x = Cq.x - A.x;  e0.y = Cq.y - A.y;  e0.z = Cq.z - A.z;  e0.w = Cq.w - A.w;
    e1.x = Dq.x - Bq.x; e1.y = Dq.y - Bq.y; e1.z = Dq.z - Bq.z; e1.w = Dq.w - Bq.w;
    *(float4*)(xbn + l * 8)     = e0;
    *(float4*)(xbn + l * 8 + 4) = e1;
    cfence();
  }

  // ---- readout at t1 (final y is in cbuf[64..79]) ----
  {
    const float o = readout_lds(cbuf, rW, rb[0]);
    if (l == 0) out[2 * b + 1] = o;
  }
}

extern "C" void kernel_launch(void* const* d_in, const int* in_sizes, int n_in,
                              void* d_out, int out_size, void* d_ws, size_t ws_size,
                              hipStream_t stream) {
  (void)in_sizes; (void)n_in; (void)out_size; (void)d_ws; (void)ws_size;
  const float* ts  = (const float*)d_in[0];
  const float* ys  = (const float*)d_in[1];
  const float* iW1 = (const float*)d_in[2];
  const float* ib1 = (const float*)d_in[3];
  const float* iW2 = (const float*)d_in[4];
  const float* ib2 = (const float*)d_in[5];
  const float* vW1 = (const float*)d_in[6];
  const float* vb1 = (const float*)d_in[7];
  const float* vW2 = (const float*)d_in[8];
  const float* vb2 = (const float*)d_in[9];
  const float* cW1 = (const float*)d_in[10];
  const float* cb1 = (const float*)d_in[11];
  const float* cW2 = (const float*)d_in[12];
  const float* cb2 = (const float*)d_in[13];
  const float* rW  = (const float*)d_in[14];
  const float* rb  = (const float*)d_in[15];
  float* out = (float*)d_out;
  hipLaunchKernelGGL(disc_kernel, dim3(512), dim3(64), 0, stream,
                     ts, ys, iW1, ib1, iW2, ib2, vW1, vb1, vW2, vb2,
                     cW1, cb1, cW2, cb2, rW, rb, out);
}